// Round 1
// baseline (170.023 us; speedup 1.0000x reference)
//
#include <hip/hip_runtime.h>
#include <stdint.h>

#define BATCH 256
#define PFD 128
#define T1 129
#define NPAIRS 1089      // 33*33
#define TSTR 132         // t-table row stride (floats), 16B-aligned
#define BKSTR 40         // b_lds row stride (bf16 elems), 80 B = 5*16B
#define CHUNK 5

typedef __attribute__((ext_vector_type(8))) short bf16x8;
typedef __attribute__((ext_vector_type(4))) float f32x4;

__device__ __forceinline__ unsigned bits_of(float f) { union { float f; unsigned u; } x; x.f = f; return x.u; }
__device__ __forceinline__ float float_of(unsigned u) { union { float f; unsigned u; } x; x.u = u; return x.f; }
__device__ __forceinline__ unsigned short bf16_rne(float f) {
  unsigned b = bits_of(f);
  return (unsigned short)((b + 0x7FFFu + ((b >> 16) & 1u)) >> 16);
}

// ---------------- Kernel 1: split-K fused trilinear GEMM ----------------
// grid = S blocks, 512 threads (8 waves). Block bk owns a contiguous range of
// (ia,iv) pairs; K runs over pair*129 + it. Output: fp32 partial [256][128]
// slab per block into d_ws.
__global__ __launch_bounds__(512, 2) void tfn_k1(
    const float* __restrict__ audio, const float* __restrict__ video,
    const float* __restrict__ text, const float* __restrict__ W1,
    float* __restrict__ part, int S) {
  __shared__ __align__(16) float t_lds[BATCH * TSTR];     // 135168 B
  __shared__ __align__(16) float av_lds[BATCH * CHUNK];   //   5120 B
  __shared__ __align__(16) short b_lds[PFD * BKSTR];      //  10240 B

  const int tid = threadIdx.x;
  const int bk = blockIdx.x;

  // pair range for this block
  const int npb = NPAIRS / S;
  const int rem = NPAIRS % S;
  const int p0 = bk * npb + (bk < rem ? bk : rem);
  const int np = npb + (bk < rem ? 1 : 0);

  // stage t-table: t_lds[m][0]=1, t_lds[m][1+c]=text[m][c]
  for (int m = tid; m < BATCH; m += 512) t_lds[m * TSTR] = 1.0f;
  for (int i = 0; i < (BATCH * 128) / 512; ++i) {
    int flat = tid + i * 512;
    int m = flat >> 7, c = flat & 127;
    t_lds[m * TSTR + 1 + c] = text[flat];
  }

  const int wave = tid >> 6, lane = tid & 63;
  const int l15 = lane & 15, quad = lane >> 4;
  const int sn = tid & 127, skg = tid >> 7;   // B-staging: column n, k-group

  f32x4 acc[2][8];
  #pragma unroll
  for (int a = 0; a < 2; ++a)
    #pragma unroll
    for (int b = 0; b < 8; ++b) acc[a][b] = f32x4{0.f, 0.f, 0.f, 0.f};

  for (int c0 = 0; c0 < np; c0 += CHUNK) {
    const int nc = (np - c0) < CHUNK ? (np - c0) : CHUNK;
    const int pbase = p0 + c0;
    __syncthreads();  // protect av_lds rewrite
    if (tid < BATCH) {
      const int m = tid;
      for (int j = 0; j < nc; ++j) {
        int p = pbase + j;
        int ia = p / 33, iv = p - ia * 33;
        float a = (ia == 0) ? 1.0f : audio[m * 32 + (ia - 1)];
        float v = (iv == 0) ? 1.0f : video[m * 32 + (iv - 1)];
        av_lds[m * CHUNK + j] = a * v;
      }
    }
    // main K-steps: per pair, it in [0,128) in 4 steps of 32
    for (int jp = 0; jp < nc; ++jp) {
      const long rowbase = (long)(pbase + jp) * T1;
      for (int s4 = 0; s4 < 4; ++s4) {
        const int it0 = s4 * 32;
        __syncthreads();
        {
          // stage W1[rowbase+it0 .. +31][0..127] -> b_lds[n][k] bf16
          // coalesced: lanes are consecutive n for fixed k
          bf16x8 v8;
          #pragma unroll
          for (int j = 0; j < 8; ++j) {
            long r = rowbase + it0 + skg * 8 + j;
            v8[j] = (short)bf16_rne(W1[r * PFD + sn]);
          }
          *(bf16x8*)&b_lds[sn * BKSTR + skg * 8] = v8;
        }
        __syncthreads();
        // A fragments (hi/lo split of fp32 product av*t)
        bf16x8 ahi[2], alo[2];
        #pragma unroll
        for (int mt = 0; mt < 2; ++mt) {
          const int m = wave * 32 + mt * 16 + l15;
          const float avv = av_lds[m * CHUNK + jp];
          const float4 ta = *(const float4*)&t_lds[m * TSTR + it0 + quad * 8];
          const float4 tb = *(const float4*)&t_lds[m * TSTR + it0 + quad * 8 + 4];
          float f[8] = { avv * ta.x, avv * ta.y, avv * ta.z, avv * ta.w,
                         avv * tb.x, avv * tb.y, avv * tb.z, avv * tb.w };
          #pragma unroll
          for (int j = 0; j < 8; ++j) {
            unsigned b = bits_of(f[j]);
            ahi[mt][j] = (short)(b >> 16);                       // truncated hi
            float resid = f[j] - float_of(b & 0xFFFF0000u);      // exact
            alo[mt][j] = (short)bf16_rne(resid);
          }
        }
        #pragma unroll
        for (int nt = 0; nt < 8; ++nt) {
          bf16x8 bf = *(const bf16x8*)&b_lds[(nt * 16 + l15) * BKSTR + quad * 8];
          acc[0][nt] = __builtin_amdgcn_mfma_f32_16x16x32_bf16(ahi[0], bf, acc[0][nt], 0, 0, 0);
          acc[0][nt] = __builtin_amdgcn_mfma_f32_16x16x32_bf16(alo[0], bf, acc[0][nt], 0, 0, 0);
          acc[1][nt] = __builtin_amdgcn_mfma_f32_16x16x32_bf16(ahi[1], bf, acc[1][nt], 0, 0, 0);
          acc[1][nt] = __builtin_amdgcn_mfma_f32_16x16x32_bf16(alo[1], bf, acc[1][nt], 0, 0, 0);
        }
      }
    }
    // remainder step: it = 128 column for each pair of this chunk (k-slot = pair idx)
    __syncthreads();
    {
      bf16x8 v8;
      #pragma unroll
      for (int j = 0; j < 8; ++j) {
        int kk = skg * 8 + j;
        short vv = 0;
        if (kk < nc) {
          long r = (long)(pbase + kk) * T1 + 128;
          vv = (short)bf16_rne(W1[r * PFD + sn]);
        }
        v8[j] = vv;
      }
      *(bf16x8*)&b_lds[sn * BKSTR + skg * 8] = v8;
    }
    __syncthreads();
    {
      bf16x8 ahi[2], alo[2];
      #pragma unroll
      for (int mt = 0; mt < 2; ++mt) {
        const int m = wave * 32 + mt * 16 + l15;
        const float t128 = t_lds[m * TSTR + 128];
        float f[8];
        #pragma unroll
        for (int j = 0; j < 8; ++j) {
          int kk = quad * 8 + j;
          f[j] = (kk < nc) ? av_lds[m * CHUNK + kk] * t128 : 0.0f;
        }
        #pragma unroll
        for (int j = 0; j < 8; ++j) {
          unsigned b = bits_of(f[j]);
          ahi[mt][j] = (short)(b >> 16);
          float resid = f[j] - float_of(b & 0xFFFF0000u);
          alo[mt][j] = (short)bf16_rne(resid);
        }
      }
      #pragma unroll
      for (int nt = 0; nt < 8; ++nt) {
        bf16x8 bf = *(const bf16x8*)&b_lds[(nt * 16 + l15) * BKSTR + quad * 8];
        acc[0][nt] = __builtin_amdgcn_mfma_f32_16x16x32_bf16(ahi[0], bf, acc[0][nt], 0, 0, 0);
        acc[0][nt] = __builtin_amdgcn_mfma_f32_16x16x32_bf16(alo[0], bf, acc[0][nt], 0, 0, 0);
        acc[1][nt] = __builtin_amdgcn_mfma_f32_16x16x32_bf16(ahi[1], bf, acc[1][nt], 0, 0, 0);
        acc[1][nt] = __builtin_amdgcn_mfma_f32_16x16x32_bf16(alo[1], bf, acc[1][nt], 0, 0, 0);
      }
    }
  }

  // write fp32 partial slab. C layout (16x16x32): col = lane&15, row = quad*4+reg
  float* po = part + (size_t)bk * (BATCH * PFD);
  #pragma unroll
  for (int mt = 0; mt < 2; ++mt)
    #pragma unroll
    for (int nt = 0; nt < 8; ++nt)
      #pragma unroll
      for (int r = 0; r < 4; ++r) {
        int m = wave * 32 + mt * 16 + quad * 4 + r;
        int n = nt * 16 + l15;
        po[m * PFD + n] = acc[mt][nt][r];
      }
}

// ---------------- Kernel 2: reduce partials + bias/relu + layers 2,3 ----------------
__global__ __launch_bounds__(128) void tfn_k2(
    const float* __restrict__ part, const float* __restrict__ b1,
    const float* __restrict__ W2, const float* __restrict__ b2,
    const float* __restrict__ W3, const float* __restrict__ b3,
    float* __restrict__ out, int S) {
  __shared__ float h1s[PFD];
  __shared__ float red[2];
  const int m = blockIdx.x, n = threadIdx.x;
  const float* p = part + m * PFD + n;
  const int STRIDE = BATCH * PFD;
  float s0 = 0, s1 = 0, s2 = 0, s3 = 0, s4 = 0, s5 = 0, s6 = 0, s7 = 0;
  int bk = 0;
  for (; bk + 8 <= S; bk += 8) {
    s0 += p[(bk + 0) * STRIDE];
    s1 += p[(bk + 1) * STRIDE];
    s2 += p[(bk + 2) * STRIDE];
    s3 += p[(bk + 3) * STRIDE];
    s4 += p[(bk + 4) * STRIDE];
    s5 += p[(bk + 5) * STRIDE];
    s6 += p[(bk + 6) * STRIDE];
    s7 += p[(bk + 7) * STRIDE];
  }
  for (; bk < S; ++bk) s0 += p[bk * STRIDE];
  float h1 = ((s0 + s1) + (s2 + s3)) + ((s4 + s5) + (s6 + s7)) + b1[n];
  h1s[n] = fmaxf(h1, 0.0f);
  __syncthreads();
  float a2 = b2[n];
  #pragma unroll 8
  for (int k = 0; k < PFD; ++k) a2 += h1s[k] * W2[k * PFD + n];
  float h2 = fmaxf(a2, 0.0f);
  float pr = h2 * W3[n];
  #pragma unroll
  for (int off = 32; off > 0; off >>= 1) pr += __shfl_down(pr, off);
  if ((n & 63) == 0) red[n >> 6] = pr;
  __syncthreads();
  if (n == 0) out[m] = red[0] + red[1] + b3[0];
}

extern "C" void kernel_launch(void* const* d_in, const int* in_sizes, int n_in,
                              void* d_out, int out_size, void* d_ws, size_t ws_size,
                              hipStream_t stream) {
  const float* audio = (const float*)d_in[0];
  const float* video = (const float*)d_in[1];
  const float* text  = (const float*)d_in[2];
  const float* W1 = (const float*)d_in[3];
  const float* b1 = (const float*)d_in[4];
  const float* W2 = (const float*)d_in[5];
  const float* b2 = (const float*)d_in[6];
  const float* W3 = (const float*)d_in[7];
  const float* b3 = (const float*)d_in[8];
  float* part = (float*)d_ws;

  const size_t slab = (size_t)BATCH * PFD * sizeof(float);
  int S = (int)(ws_size / slab);
  if (S > 256) S = 256;
  if (S < 1) S = 1;

  tfn_k1<<<S, 512, 0, stream>>>(audio, video, text, W1, part, S);
  tfn_k2<<<BATCH, PFD, 0, stream>>>(part, b1, W2, b2, W3, b3, (float*)d_out, S);
}

// Round 2
// 151.880 us; speedup vs baseline: 1.1195x; 1.1195x over previous
//
#include <hip/hip_runtime.h>
#include <stdint.h>

#define BATCH 256
#define PFD 128
#define T1 129
#define NPAIRS 1089      // 33*33
#define TSTR 132         // t-table row stride (floats), 528 B, 16B-aligned
#define BK 64            // K-tile rows per staging step
#define BKSTR 72         // b_lds row stride (bf16 elems), 144 B = 16B-aligned, 2-way banks only
#define CHUNK 8

typedef short bf16x8 __attribute__((ext_vector_type(8)));
typedef float f32x4 __attribute__((ext_vector_type(4)));

__device__ __forceinline__ unsigned bits_of(float f) { union { float f; unsigned u; } x; x.f = f; return x.u; }
__device__ __forceinline__ float float_of(unsigned u) { union { float f; unsigned u; } x; x.u = u; return x.f; }
__device__ __forceinline__ unsigned short bf16_rne(float f) {
  unsigned b = bits_of(f);
  return (unsigned short)((b + 0x7FFFu + ((b >> 16) & 1u)) >> 16);
}
__device__ __forceinline__ float bf2f(unsigned short u) { return float_of(((unsigned)u) << 16); }

// ---------------- Kernel 1: split-K fused trilinear GEMM (pipelined) ----------------
// grid = S blocks, 512 threads (8 waves). Block owns a contiguous (ia,iv)-pair
// range; K = pair*129 + it. Pipeline: prefetch next 64-row W1 tile into VGPRs
// while MFMA-ing the current tile from LDS. Partials stored bf16, n-swizzled
// (physical idx = (n&15)*8 + (n>>4)) so each lane writes one 16B bf16x8.
__global__ __launch_bounds__(512, 2) void tfn_k1(
    const float* __restrict__ audio, const float* __restrict__ video,
    const float* __restrict__ text, const float* __restrict__ W1,
    unsigned short* __restrict__ part, int S) {
  __shared__ __align__(16) float t_lds[BATCH * TSTR];     // 135168 B
  __shared__ __align__(16) float av_lds[BATCH * CHUNK];   //   8192 B
  __shared__ __align__(16) short b_lds[PFD * BKSTR];      //  18432 B  -> 161792 total

  const int tid = threadIdx.x;
  const int bk = blockIdx.x;

  const int npb = NPAIRS / S;
  const int rem = NPAIRS % S;
  const int p0 = bk * npb + (bk < rem ? bk : rem);
  const int np = npb + (bk < rem ? 1 : 0);

  // stage t-table: col 0 = 1.0, cols 1..128 = text (vector global reads)
  for (int i = tid; i < BATCH * 32; i += 512) {
    int m = i >> 5, g = (i & 31) * 4;
    const float4 v = *(const float4*)&text[m * 128 + g];
    float* dst = &t_lds[m * TSTR + 1 + g];
    dst[0] = v.x; dst[1] = v.y; dst[2] = v.z; dst[3] = v.w;
  }
  if (tid < BATCH) t_lds[tid * TSTR] = 1.0f;

  const int wave = tid >> 6, lane = tid & 63;
  const int l15 = lane & 15, quad = lane >> 4;
  const int sn = tid & 127, skg = tid >> 7;   // staging: column n, k-group

  f32x4 acc[2][8];
  #pragma unroll
  for (int a = 0; a < 2; ++a)
    #pragma unroll
    for (int b = 0; b < 8; ++b) acc[a][b] = f32x4{0.f, 0.f, 0.f, 0.f};

  float pf[16];

  for (int c0 = 0; c0 < np; c0 += CHUNK) {
    const int nc = (np - c0) < CHUNK ? (np - c0) : CHUNK;
    const int pbase = p0 + c0;
    __syncthreads();  // prev chunk compute done; t_lds staged (first iter)
    if (tid < BATCH) {
      const int m = tid;
      for (int j = 0; j < nc; ++j) {
        int p = pbase + j;
        int ia = p / 33, iv = p - ia * 33;
        float a = (ia == 0) ? 1.0f : audio[m * 32 + (ia - 1)];
        float v = (iv == 0) ? 1.0f : video[m * 32 + (iv - 1)];
        av_lds[m * CHUNK + j] = a * v;
      }
    }
    const int ntiles = nc * 2;   // 2 tiles of 64 k-rows per pair (it 0..127)
    // prefetch tile 0
    {
      const long rowbase = (long)pbase * T1;
      #pragma unroll
      for (int g = 0; g < 2; ++g)
        #pragma unroll
        for (int j = 0; j < 8; ++j)
          pf[g * 8 + j] = W1[(rowbase + g * 32 + skg * 8 + j) * PFD + sn];
    }
    for (int s = 0; s < ntiles; ++s) {
      __syncthreads();          // b_lds free (prev tile's MFMAs done); av visible
      {
        bf16x8 w0, w1;
        #pragma unroll
        for (int j = 0; j < 8; ++j) {
          w0[j] = (short)bf16_rne(pf[j]);
          w1[j] = (short)bf16_rne(pf[8 + j]);
        }
        *(bf16x8*)&b_lds[sn * BKSTR + skg * 8] = w0;
        *(bf16x8*)&b_lds[sn * BKSTR + 32 + skg * 8] = w1;
      }
      __syncthreads();          // b_lds ready
      // issue next tile's loads now; latency overlaps with compute below
      if (s + 1 < ntiles) {
        const int jp1 = (s + 1) >> 1, h1 = (s + 1) & 1;
        const long rowbase = (long)(pbase + jp1) * T1 + h1 * 64;
        #pragma unroll
        for (int g = 0; g < 2; ++g)
          #pragma unroll
          for (int j = 0; j < 8; ++j)
            pf[g * 8 + j] = W1[(rowbase + g * 32 + skg * 8 + j) * PFD + sn];
      }
      // compute tile s
      const int jp = s >> 1, itb = (s & 1) * 64;
      #pragma unroll
      for (int ks = 0; ks < 64; ks += 32) {
        bf16x8 ahi[2], alo[2];
        #pragma unroll
        for (int mt = 0; mt < 2; ++mt) {
          const int m = wave * 32 + mt * 16 + l15;
          const float avv = av_lds[m * CHUNK + jp];
          const float4 ta = *(const float4*)&t_lds[m * TSTR + itb + ks + quad * 8];
          const float4 tb = *(const float4*)&t_lds[m * TSTR + itb + ks + quad * 8 + 4];
          float f[8] = { avv * ta.x, avv * ta.y, avv * ta.z, avv * ta.w,
                         avv * tb.x, avv * tb.y, avv * tb.z, avv * tb.w };
          #pragma unroll
          for (int j = 0; j < 8; ++j) {
            unsigned b = bits_of(f[j]);
            ahi[mt][j] = (short)(b >> 16);                      // truncated hi
            alo[mt][j] = (short)bf16_rne(f[j] - float_of(b & 0xFFFF0000u));
          }
        }
        #pragma unroll
        for (int nt = 0; nt < 8; ++nt) {
          bf16x8 bf = *(const bf16x8*)&b_lds[(nt * 16 + l15) * BKSTR + ks + quad * 8];
          acc[0][nt] = __builtin_amdgcn_mfma_f32_16x16x32_bf16(ahi[0], bf, acc[0][nt], 0, 0, 0);
          acc[0][nt] = __builtin_amdgcn_mfma_f32_16x16x32_bf16(alo[0], bf, acc[0][nt], 0, 0, 0);
          acc[1][nt] = __builtin_amdgcn_mfma_f32_16x16x32_bf16(ahi[1], bf, acc[1][nt], 0, 0, 0);
          acc[1][nt] = __builtin_amdgcn_mfma_f32_16x16x32_bf16(alo[1], bf, acc[1][nt], 0, 0, 0);
        }
      }
    }
    // remainder tile: the it=128 column for this chunk's pairs (k-slot j = pair j)
    __syncthreads();
    {
      bf16x8 w = {0, 0, 0, 0, 0, 0, 0, 0};
      if (skg == 0) {
        #pragma unroll
        for (int j = 0; j < 8; ++j)
          if (j < nc) w[j] = (short)bf16_rne(W1[((long)(pbase + j) * T1 + 128) * PFD + sn]);
      }
      *(bf16x8*)&b_lds[sn * BKSTR + skg * 8] = w;
    }
    __syncthreads();
    {
      bf16x8 ahi[2], alo[2];
      #pragma unroll
      for (int mt = 0; mt < 2; ++mt) {
        const int m = wave * 32 + mt * 16 + l15;
        const float t128 = t_lds[m * TSTR + 128];
        float f[8];
        #pragma unroll
        for (int j = 0; j < 8; ++j) {
          int kk = quad * 8 + j;
          f[j] = (kk < nc) ? av_lds[m * CHUNK + kk] * t128 : 0.0f;
        }
        #pragma unroll
        for (int j = 0; j < 8; ++j) {
          unsigned b = bits_of(f[j]);
          ahi[mt][j] = (short)(b >> 16);
          alo[mt][j] = (short)bf16_rne(f[j] - float_of(b & 0xFFFF0000u));
        }
      }
      #pragma unroll
      for (int nt = 0; nt < 8; ++nt) {
        bf16x8 bf = *(const bf16x8*)&b_lds[(nt * 16 + l15) * BKSTR + quad * 8];
        acc[0][nt] = __builtin_amdgcn_mfma_f32_16x16x32_bf16(ahi[0], bf, acc[0][nt], 0, 0, 0);
        acc[0][nt] = __builtin_amdgcn_mfma_f32_16x16x32_bf16(alo[0], bf, acc[0][nt], 0, 0, 0);
        acc[1][nt] = __builtin_amdgcn_mfma_f32_16x16x32_bf16(ahi[1], bf, acc[1][nt], 0, 0, 0);
        acc[1][nt] = __builtin_amdgcn_mfma_f32_16x16x32_bf16(alo[1], bf, acc[1][nt], 0, 0, 0);
      }
    }
  }

  // writeback: bf16, n-swizzled so each lane stores one contiguous bf16x8.
  // C layout (16x16x32): col = lane&15, row = quad*4+reg. physical n-idx = l15*8+nt.
  unsigned short* po = part + (size_t)bk * (BATCH * PFD);
  #pragma unroll
  for (int mt = 0; mt < 2; ++mt)
    #pragma unroll
    for (int r = 0; r < 4; ++r) {
      const int m = wave * 32 + mt * 16 + quad * 4 + r;
      bf16x8 w;
      #pragma unroll
      for (int nt = 0; nt < 8; ++nt) w[nt] = (short)bf16_rne(acc[mt][nt][r]);
      *(bf16x8*)&po[m * PFD + l15 * 8] = w;
    }
}

// ---------------- Kernel 2: reduce partials + bias/relu + layers 2,3 ----------------
__global__ __launch_bounds__(256) void tfn_k2(
    const unsigned short* __restrict__ part, const float* __restrict__ b1,
    const float* __restrict__ W2, const float* __restrict__ b2,
    const float* __restrict__ W3, const float* __restrict__ b3,
    float* __restrict__ out, int S) {
  __shared__ float sred[256];
  __shared__ float a2s[256];
  __shared__ float h1s[PFD];
  __shared__ float red[2];
  const int m = blockIdx.x, tid = threadIdx.x;
  const int n = tid & 127, half = tid >> 7;
  const int phys = (n & 15) * 8 + (n >> 4);           // un-swizzle
  const unsigned short* base = part + m * PFD + phys;
  const size_t STR = (size_t)BATCH * PFD;
  float s0 = 0, s1 = 0, s2 = 0, s3 = 0, s4 = 0, s5 = 0, s6 = 0, s7 = 0;
  int bk = half;
  for (; bk + 14 < S; bk += 16) {
    s0 += bf2f(base[(bk +  0) * STR]);
    s1 += bf2f(base[(bk +  2) * STR]);
    s2 += bf2f(base[(bk +  4) * STR]);
    s3 += bf2f(base[(bk +  6) * STR]);
    s4 += bf2f(base[(bk +  8) * STR]);
    s5 += bf2f(base[(bk + 10) * STR]);
    s6 += bf2f(base[(bk + 12) * STR]);
    s7 += bf2f(base[(bk + 14) * STR]);
  }
  for (; bk < S; bk += 2) s0 += bf2f(base[bk * STR]);
  sred[tid] = ((s0 + s1) + (s2 + s3)) + ((s4 + s5) + (s6 + s7));
  __syncthreads();
  if (half == 0) h1s[n] = fmaxf(sred[n] + sred[n + 128] + b1[n], 0.0f);
  __syncthreads();
  float a2 = 0.0f;
  const int k0 = half * 64;
  #pragma unroll 8
  for (int k = 0; k < 64; ++k) a2 += h1s[k0 + k] * W2[(k0 + k) * PFD + n];
  a2s[tid] = a2;
  __syncthreads();
  if (half == 0) {
    float h2 = fmaxf(a2s[n] + a2s[n + 128] + b2[n], 0.0f);
    float pr = h2 * W3[n];
    #pragma unroll
    for (int off = 32; off > 0; off >>= 1) pr += __shfl_down(pr, off);
    if ((tid & 63) == 0) red[tid >> 6] = pr;
  }
  __syncthreads();
  if (tid == 0) out[m] = red[0] + red[1] + b3[0];
}

extern "C" void kernel_launch(void* const* d_in, const int* in_sizes, int n_in,
                              void* d_out, int out_size, void* d_ws, size_t ws_size,
                              hipStream_t stream) {
  const float* audio = (const float*)d_in[0];
  const float* video = (const float*)d_in[1];
  const float* text  = (const float*)d_in[2];
  const float* W1 = (const float*)d_in[3];
  const float* b1 = (const float*)d_in[4];
  const float* W2 = (const float*)d_in[5];
  const float* b2 = (const float*)d_in[6];
  const float* W3 = (const float*)d_in[7];
  const float* b3 = (const float*)d_in[8];
  unsigned short* part = (unsigned short*)d_ws;

  const size_t slab = (size_t)BATCH * PFD * sizeof(unsigned short);  // 64 KB
  int S = (int)(ws_size / slab);
  if (S > 256) S = 256;
  if (S < 1) S = 1;

  tfn_k1<<<S, 512, 0, stream>>>(audio, video, text, W1, part, S);
  tfn_k2<<<BATCH, 256, 0, stream>>>(part, b1, W2, b2, W3, b3, (float*)d_out, S);
}